// Round 15
// baseline (705.947 us; speedup 1.0000x reference)
//
#include <hip/hip_runtime.h>
#include <cstdint>

#define NH 12
#define HD 64
#define NSEQ 2048
#define CDIM 768
#define NB 2

typedef __attribute__((ext_vector_type(2))) float f32x2;

// ---------------------------------------------------------------------------
// Kernel 1 (fused): blocks [0,768): Q,K = x @ qkv_w[0:1536]^T, f64 accum,
// 128x64 tile, 8x4/thread, f64 LDS staging (double2 reads), reg-prefetch.
// blocks [768,1536): V = x @ qkv_w[1536:2304]^T, f32, 64x64 tile, 4x4/thread.
// ---------------------------------------------------------------------------
__global__ __launch_bounds__(256, 4) void qkv_fused(const float* __restrict__ x,
                                                    const float* __restrict__ w,
                                                    double* __restrict__ Q64,
                                                    double* __restrict__ K64,
                                                    float* __restrict__ Qs32,
                                                    float* __restrict__ Kt32,
                                                    float* __restrict__ V) {
    __shared__ __align__(16) char smem[24576];
    const int tid = threadIdx.x;

    if (blockIdx.x < 768) {
        // ---------------- Q,K path (f64) ----------------
        double (*As)[128] = reinterpret_cast<double(*)[128]>(smem);          // 16 KB
        double (*Bs)[64]  = reinterpret_cast<double(*)[64]>(smem + 16384);   // 8 KB
        const int bm = (blockIdx.x / 24) * 128;   // M = 4096
        const int bn = (blockIdx.x % 24) * 64;    // N = 1536
        const int alm = tid >> 1, alk = (tid & 1) * 8;
        const int blm = tid & 63, blk = (tid >> 6) * 4;
        const int tx = tid & 15, ty = tid >> 4;

        double acc[8][4] = {};
        float4 a0 = *reinterpret_cast<const float4*>(&x[(bm + alm) * CDIM + alk]);
        float4 a1 = *reinterpret_cast<const float4*>(&x[(bm + alm) * CDIM + alk + 4]);
        float4 b0 = *reinterpret_cast<const float4*>(&w[(bn + blm) * CDIM + blk]);
        for (int k0 = 0; k0 < CDIM; k0 += 16) {
            __syncthreads();
            As[alk + 0][alm] = (double)a0.x; As[alk + 1][alm] = (double)a0.y;
            As[alk + 2][alm] = (double)a0.z; As[alk + 3][alm] = (double)a0.w;
            As[alk + 4][alm] = (double)a1.x; As[alk + 5][alm] = (double)a1.y;
            As[alk + 6][alm] = (double)a1.z; As[alk + 7][alm] = (double)a1.w;
            Bs[blk + 0][blm] = (double)b0.x; Bs[blk + 1][blm] = (double)b0.y;
            Bs[blk + 2][blm] = (double)b0.z; Bs[blk + 3][blm] = (double)b0.w;
            __syncthreads();
            if (k0 + 16 < CDIM) {
                a0 = *reinterpret_cast<const float4*>(&x[(bm + alm) * CDIM + k0 + 16 + alk]);
                a1 = *reinterpret_cast<const float4*>(&x[(bm + alm) * CDIM + k0 + 16 + alk + 4]);
                b0 = *reinterpret_cast<const float4*>(&w[(bn + blm) * CDIM + k0 + 16 + blk]);
            }
#pragma unroll
            for (int k = 0; k < 16; ++k) {
                double2 a01 = *reinterpret_cast<const double2*>(&As[k][ty * 8 + 0]);
                double2 a23 = *reinterpret_cast<const double2*>(&As[k][ty * 8 + 2]);
                double2 a45 = *reinterpret_cast<const double2*>(&As[k][ty * 8 + 4]);
                double2 a67 = *reinterpret_cast<const double2*>(&As[k][ty * 8 + 6]);
                double2 b01 = *reinterpret_cast<const double2*>(&Bs[k][tx * 4 + 0]);
                double2 b23 = *reinterpret_cast<const double2*>(&Bs[k][tx * 4 + 2]);
                double ad[8] = {a01.x, a01.y, a23.x, a23.y, a45.x, a45.y, a67.x, a67.y};
                double bd[4] = {b01.x, b01.y, b23.x, b23.y};
#pragma unroll
                for (int i = 0; i < 8; ++i)
#pragma unroll
                    for (int j = 0; j < 4; ++j) acc[i][j] = fma(ad[i], bd[j], acc[i][j]);
            }
        }
        const bool isQ = bn < CDIM;
        const int hh = (isQ ? bn : bn - CDIM) >> 6;
        const int b  = bm >> 11;
        const int bh = b * NH + hh;
#pragma unroll
        for (int i = 0; i < 8; ++i) {
            const int n = (bm + ty * 8 + i) & (NSEQ - 1);
            const size_t base = ((size_t)bh * NSEQ + n) * HD + tx * 4;
            double2 d01; d01.x = acc[i][0]; d01.y = acc[i][1];
            double2 d23; d23.x = acc[i][2]; d23.y = acc[i][3];
            if (isQ) {
                *reinterpret_cast<double2*>(&Q64[base]) = d01;
                *reinterpret_cast<double2*>(&Q64[base + 2]) = d23;
                *reinterpret_cast<float4*>(&Qs32[base]) =
                    make_float4((float)acc[i][0], (float)acc[i][1], (float)acc[i][2], (float)acc[i][3]);
            } else {
                *reinterpret_cast<double2*>(&K64[base]) = d01;
                *reinterpret_cast<double2*>(&K64[base + 2]) = d23;
#pragma unroll
                for (int j = 0; j < 4; ++j)
                    Kt32[((size_t)bh * HD + tx * 4 + j) * NSEQ + n] = (float)acc[i][j];
            }
        }
    } else {
        // ---------------- V path (f32) ----------------
        float (*As)[64] = reinterpret_cast<float(*)[64]>(smem);              // 4 KB
        float (*Bs)[64] = reinterpret_cast<float(*)[64]>(smem + 4096);       // 4 KB
        const float* __restrict__ wv = w + (size_t)2 * CDIM * CDIM;
        const int vid = blockIdx.x - 768;
        const int bm = (vid / 12) * 64;
        const int bn = (vid % 12) * 64;
        const int lm = tid >> 2;
        const int lk = (tid & 3) << 2;
        const int tx = tid & 15, ty = tid >> 4;

        float acc[4][4] = {};
        float4 av = *reinterpret_cast<const float4*>(&x[(bm + lm) * CDIM + lk]);
        float4 bv = *reinterpret_cast<const float4*>(&wv[(bn + lm) * CDIM + lk]);
        for (int k0 = 0; k0 < CDIM; k0 += 16) {
            __syncthreads();
            As[lk + 0][lm] = av.x; As[lk + 1][lm] = av.y; As[lk + 2][lm] = av.z; As[lk + 3][lm] = av.w;
            Bs[lk + 0][lm] = bv.x; Bs[lk + 1][lm] = bv.y; Bs[lk + 2][lm] = bv.z; Bs[lk + 3][lm] = bv.w;
            __syncthreads();
            if (k0 + 16 < CDIM) {
                av = *reinterpret_cast<const float4*>(&x[(bm + lm) * CDIM + k0 + 16 + lk]);
                bv = *reinterpret_cast<const float4*>(&wv[(bn + lm) * CDIM + k0 + 16 + lk]);
            }
#pragma unroll
            for (int k = 0; k < 16; ++k) {
                float4 a4 = *reinterpret_cast<const float4*>(&As[k][ty * 4]);
                float4 b4 = *reinterpret_cast<const float4*>(&Bs[k][tx * 4]);
                float aa[4] = {a4.x, a4.y, a4.z, a4.w};
                float bb[4] = {b4.x, b4.y, b4.z, b4.w};
#pragma unroll
                for (int i = 0; i < 4; ++i)
#pragma unroll
                    for (int j = 0; j < 4; ++j) acc[i][j] = fmaf(aa[i], bb[j], acc[i][j]);
            }
        }
        const int hh = bn >> 6;
        const int b  = bm >> 11;
#pragma unroll
        for (int i = 0; i < 4; ++i) {
            const int n = (bm + ty * 4 + i) & (NSEQ - 1);
            *reinterpret_cast<float4*>(&V[(((size_t)b * NH + hh) * NSEQ + n) * HD + tx * 4]) =
                make_float4(acc[i][0], acc[i][1], acc[i][2], acc[i][3]);
        }
    }
}

// ---------------------------------------------------------------------------
// Kernel 2: packed-f32 bulk scores (explicit v_pk_fma_f32) -> u16-key
// candidates (ballot select) -> group-coalesced dynamic f64 rescore ->
// packed bitonic (top-64-only merge) -> exact f64 softmax/top-p -> sparse PV.
// XCD-swizzled blocks. 512 threads (8 waves), 8 rows/block; wave w owns row w.
// ---------------------------------------------------------------------------
__device__ inline unsigned long long d2key(double f) {
    unsigned long long u = (unsigned long long)__double_as_longlong(f);
    return u ^ (unsigned long long)(((long long)u >> 63) | (long long)0x8000000000000000ull);
}
__device__ inline double key2d(unsigned long long k) {
    unsigned long long mask = ((long long)k < 0) ? 0x8000000000000000ull : 0xFFFFFFFFFFFFFFFFull;
    return __longlong_as_double((long long)(k ^ mask));
}
__device__ inline unsigned kp(float a, float b) {
    unsigned ua = __float_as_uint(a);
    ua ^= (unsigned)(((int)ua >> 31) | 0x80000000);
    unsigned ub = __float_as_uint(b);
    ub ^= (unsigned)(((int)ub >> 31) | 0x80000000);
    return (ua >> 16) | (ub & 0xFFFF0000u);
}

__global__ __launch_bounds__(512, 6) void attn_kernel(const double* __restrict__ Q64,
                                                      const double* __restrict__ K64,
                                                      const float* __restrict__ Qs32,
                                                      const float* __restrict__ Kt32,
                                                      const float* __restrict__ V,
                                                      const float* __restrict__ temp,
                                                      const int* __restrict__ topk_p,
                                                      float* __restrict__ AO) {
    __shared__ unsigned short sk[8][NSEQ];   // 32 KB u16 proxy keys (row r's first
                                             // 1 KB later reused as packed-key scratch)
    __shared__ int cand[8][128];

    const int tid  = threadIdx.x;              // 0..511
    // XCD swizzle: nwg=6144 (%8==0). Same-XCD blocks get 768 consecutive work
    // items = 3 whole (b,h) K-panels -> panel stays L2-resident per XCD.
    const int wg   = (blockIdx.x & 7) * 768 + (blockIdx.x >> 3);
    const int bh   = wg >> 8;
    const int g0   = (wg & 255) << 3;
    const int lane = tid & 63;
    const int wv   = tid >> 6;

    const double scale = 0.125 * (double)temp[0];
    const float sc32 = (float)scale;
    int TK = *topk_p;
    if (TK > 64) TK = 64;
    if (TK < 1)  TK = 1;

    // ---- phase 2: raw f32 dots via explicit v_pk_fma_f32 (2 FMA/lane/instr).
    // Per-component semantics identical to the scalar fmaf chain -> scores
    // bit-identical; decision chain unaffected.
    const float* __restrict__ kb = Kt32 + (size_t)bh * HD * NSEQ;
    const float* __restrict__ qp = Qs32 + ((size_t)bh * NSEQ + g0) * HD;  // qp[r*64+d]
    const int m0 = tid * 4;
    f32x2 acc2[8][2] = {};
#pragma unroll 4
    for (int d = 0; d < HD; ++d) {
        float4 k4 = *reinterpret_cast<const float4*>(&kb[(size_t)d * NSEQ + m0]);
        f32x2 kA; kA.x = k4.x; kA.y = k4.y;
        f32x2 kB; kB.x = k4.z; kB.y = k4.w;
#pragma unroll
        for (int r8 = 0; r8 < 8; ++r8) {
            float qv = qp[r8 * HD + d];
            f32x2 qq; qq.x = qv; qq.y = qv;
            asm("v_pk_fma_f32 %0, %1, %2, %0"
                : "+v"(acc2[r8][0]) : "v"(qq), "v"(kA));
            asm("v_pk_fma_f32 %0, %1, %2, %0"
                : "+v"(acc2[r8][1]) : "v"(qq), "v"(kB));
        }
    }
#pragma unroll
    for (int r8 = 0; r8 < 8; ++r8) {
        uint2 pkv;
        pkv.x = kp(acc2[r8][0].x * sc32, acc2[r8][0].y * sc32);
        pkv.y = kp(acc2[r8][1].x * sc32, acc2[r8][1].y * sc32);
        *reinterpret_cast<uint2*>(&sk[r8][m0]) = pkv;
    }
    __syncthreads();

    // ---- phase 3: wave wv owns row wv
    const int r = wv;
    const int row = g0 + r;

    int k32[32];
#pragma unroll
    for (int i = 0; i < 32; ++i) k32[i] = sk[r][i * 64 + lane];

    // wave max of keys
    int mx = k32[0];
#pragma unroll
    for (int i = 1; i < 32; ++i) mx = max(mx, k32[i]);
#pragma unroll
    for (int off = 32; off > 0; off >>= 1) mx = max(mx, __shfl_xor(mx, off));

    // windowed binary search on u16 keys via ballot+popc:
    // largest lo with count(>=lo) >= TK, stop once that count <= 72.
    int lo0 = mx > 512 ? mx - 512 : 0;
    int c0 = 0;
#pragma unroll
    for (int i = 0; i < 32; ++i) c0 += (int)__popcll(__ballot(k32[i] >= lo0));
    int lo, hi, clo;
    if (c0 >= TK) { lo = lo0; clo = c0; hi = mx; }
    else          { lo = 0;   clo = NSEQ; hi = lo0 - 1; }
    while (lo < hi && clo > 72) {
        int mid = lo + ((hi - lo + 1) >> 1);
        int c = 0;
#pragma unroll
        for (int i = 0; i < 32; ++i) c += (int)__popcll(__ballot(k32[i] >= mid));
        if (c >= TK) { lo = mid; clo = c; } else hi = mid - 1;
    }
    int thr = lo >= 2 ? lo - 2 : 0;   // margin covers f32-dot + trunc error

    // ballot-based compaction of candidate column indices (deterministic order)
    const unsigned long long lmask = (1ull << lane) - 1ull;
    int base = 0;
#pragma unroll
    for (int i = 0; i < 32; ++i) {
        bool pred = k32[i] >= thr;
        unsigned long long bal = __ballot(pred);
        if (pred) {
            int slot = base + (int)__popcll(bal & lmask);
            if (slot < 128) cand[r][slot] = i * 64 + lane;
        }
        base += (int)__popcll(bal);
    }
    int ncand = min(base, 128);
    asm volatile("s_waitcnt lgkmcnt(0)" ::: "memory");

    // ---- group-coalesced dynamic f64 rescore: 8 groups x 8 lanes;
    // iteration j covers slots j*8 + gidx; lane sl reads k[m][sl*8..sl*8+8)
    const int gidx = lane >> 3;
    const int sl   = lane & 7;
    const double* __restrict__ qrow = Q64 + ((size_t)bh * NSEQ + row) * HD;
    double qd[8];
#pragma unroll
    for (int j = 0; j < 8; ++j) qd[j] = qrow[sl * 8 + j];

    // prefetch all candidate indices for this lane's group into registers
    int msArr[16];
#pragma unroll
    for (int j = 0; j < 16; ++j) msArr[j] = cand[r][min(j * 8 + gidx, ncand - 1)];

    unsigned long long* pkr = reinterpret_cast<unsigned long long*>(&sk[r][0]);
    pkr[lane] = 0ull;                 // zero-init packed-key scratch (128 slots)
    pkr[64 + lane] = 0ull;
    const double* __restrict__ kbase = K64 + (size_t)bh * NSEQ * HD;
    const int jmax = (ncand + 7) >> 3;    // wave-uniform
#pragma unroll 2
    for (int j = 0; j < jmax; ++j) {
        const int s = j * 8 + gidx;
        const int ms = msArr[j];
        const double* __restrict__ kp8 = kbase + (size_t)ms * HD + sl * 8;
        double a = 0.0;
#pragma unroll
        for (int d = 0; d < 8; ++d) a = fma(qd[d], kp8[d], a);
        // 8-lane tree reduction (deterministic f64 order)
        a += __shfl_xor(a, 1);
        a += __shfl_xor(a, 2);
        a += __shfl_xor(a, 4);
        a *= scale;
        unsigned long long pkv = (d2key(a) & ~2047ull) | (unsigned long long)(2047 - ms);
        if (sl == (j & 7) && s < ncand) pkr[s] = pkv;
    }
    asm volatile("s_waitcnt lgkmcnt(0)" ::: "memory");
    unsigned long long pk1 = pkr[lane];
    unsigned long long pk2 = pkr[64 + lane];

    // bitonic: sort t0 asc, t1 desc (by t), then top-64-only final merge.
    unsigned long long t0 = ~pk1, t1 = ~pk2;
#pragma unroll
    for (int k = 2; k <= 64; k <<= 1) {
#pragma unroll
        for (int j = k >> 1; j > 0; j >>= 1) {
            {
                unsigned long long ot = __shfl_xor(t0, j);
                bool dir = (lane & k) != 0;
                bool lower = (lane & j) == 0;
                bool takeMin = (lower != dir);
                bool less = t0 < ot;
                t0 = (takeMin == less) ? t0 : ot;
            }
            {
                unsigned long long ot = __shfl_xor(t1, j);
                bool dir = (k == 64) ? true : ((lane & k) != 0);
                bool lower = (lane & j) == 0;
                bool takeMin = (lower != dir);
                bool less = t1 < ot;
                t1 = (takeMin == less) ? t1 : ot;
            }
        }
    }
    // k=128 split: after pairwise min, t0 holds the 64 largest keys (bitonic);
    // TK <= 64 so t1's merge is dead work — sort only t0.
    t0 = (t1 < t0) ? t1 : t0;
#pragma unroll
    for (int j = 32; j > 0; j >>= 1) {
        unsigned long long ot = __shfl_xor(t0, j);
        bool lower = (lane & j) == 0;
        bool less = t0 < ot;
        t0 = (lower == less) ? t0 : ot;
    }
    // lane l holds l-th largest candidate
    unsigned long long kk = ~t0;
    int mi = 2047 - (int)(kk & 2047ull);
    bool valid = lane < TK;
    double a = valid ? key2d(kk & ~2047ull) : 0.0;
    double amax = __shfl(a, 0);
    double s = valid ? exp(a - amax) : 0.0;

    double ps = s;
#pragma unroll
    for (int off = 1; off < 64; off <<= 1) {
        double tt = __shfl_up(ps, off);
        if (lane >= off) ps += tt;
    }
    double S = __shfl(ps, 63);
    double cumprev = (ps - s) / S;
    bool keep = valid && ((lane == 0) || (cumprev <= 0.9));
    double sk2 = keep ? s : 0.0;
    double S2 = sk2;
#pragma unroll
    for (int off = 32; off > 0; off >>= 1) S2 += __shfl_xor(S2, off);
    float p = (float)(keep ? (s / S2) : 0.0);

    unsigned long long bal = __ballot(keep);
    int nk = __popcll(bal);

    // sparse PV, 4-way accumulators (f32 reorder only; decisions unaffected)
    const float* __restrict__ vb = V + (size_t)bh * NSEQ * HD;
    float o0 = 0.f, o1 = 0.f, o2 = 0.f, o3 = 0.f;
    int i = 0;
    for (; i + 4 <= nk; i += 4) {
        float pa = __shfl(p, i),     pb = __shfl(p, i + 1);
        float pc = __shfl(p, i + 2), pd = __shfl(p, i + 3);
        int ma = __shfl(mi, i),     mb2 = __shfl(mi, i + 1);
        int mc = __shfl(mi, i + 2), md = __shfl(mi, i + 3);
        o0 = fmaf(pa, vb[(size_t)ma * HD + lane], o0);
        o1 = fmaf(pb, vb[(size_t)mb2 * HD + lane], o1);
        o2 = fmaf(pc, vb[(size_t)mc * HD + lane], o2);
        o3 = fmaf(pd, vb[(size_t)md * HD + lane], o3);
    }
    for (; i < nk; ++i) {
        float pi = __shfl(p, i);
        int midx = __shfl(mi, i);
        o0 = fmaf(pi, vb[(size_t)midx * HD + lane], o0);
    }
    float o = (o0 + o1) + (o2 + o3);
    const int b = bh / NH, hh = bh % NH;
    AO[((size_t)b * NSEQ + row) * CDIM + hh * HD + lane] = o;
}

// ---------------------------------------------------------------------------
// Kernel 3: out = AO @ proj_w^T + proj_b   (f32, 128x64 tile, 8x4/thread)
// ---------------------------------------------------------------------------
__global__ __launch_bounds__(256) void proj_gemm(const float* __restrict__ A,
                                                 const float* __restrict__ w,
                                                 const float* __restrict__ bias,
                                                 float* __restrict__ out) {
    __shared__ float As[16][128];
    __shared__ float Bs[16][64];
    const int tid = threadIdx.x;
    const int bm = blockIdx.y * 128;
    const int bn = blockIdx.x * 64;
    const int alm = tid >> 1, alk = (tid & 1) * 8;
    const int blm = tid & 63, blk = (tid >> 6) * 4;
    const int tx = tid & 15, ty = tid >> 4;

    float acc[8][4] = {};
    float4 a0 = *reinterpret_cast<const float4*>(&A[(bm + alm) * CDIM + alk]);
    float4 a1 = *reinterpret_cast<const float4*>(&A[(bm + alm) * CDIM + alk + 4]);
    float4 b0 = *reinterpret_cast<const float4*>(&w[(bn + blm) * CDIM + blk]);
    for (int k0 = 0; k0 < CDIM; k0 += 16) {
        __syncthreads();
        As[alk + 0][alm] = a0.x; As[alk + 1][alm] = a0.y;
        As[alk + 2][alm] = a0.z; As[alk + 3][alm] = a0.w;
        As[alk + 4][alm] = a1.x; As[alk + 5][alm] = a1.y;
        As[alk + 6][alm] = a1.z; As[alk + 7][alm] = a1.w;
        Bs[blk + 0][blm] = b0.x; Bs[blk + 1][blm] = b0.y;
        Bs[blk + 2][blm] = b0.z; Bs[blk + 3][blm] = b0.w;
        __syncthreads();
        if (k0 + 16 < CDIM) {
            a0 = *reinterpret_cast<const float4*>(&A[(bm + alm) * CDIM + k0 + 16 + alk]);
            a1 = *reinterpret_cast<const float4*>(&A[(bm + alm) * CDIM + k0 + 16 + alk + 4]);
            b0 = *reinterpret_cast<const float4*>(&w[(bn + blm) * CDIM + k0 + 16 + blk]);
        }
#pragma unroll
        for (int k = 0; k < 16; ++k) {
            float4 af0 = *reinterpret_cast<const float4*>(&As[k][ty * 8]);
            float4 af1 = *reinterpret_cast<const float4*>(&As[k][ty * 8 + 4]);
            float4 bf  = *reinterpret_cast<const float4*>(&Bs[k][tx * 4]);
            float aa[8] = {af0.x, af0.y, af0.z, af0.w, af1.x, af1.y, af1.z, af1.w};
            float bb[4] = {bf.x, bf.y, bf.z, bf.w};
#pragma unroll
            for (int i = 0; i < 8; ++i)
#pragma unroll
                for (int j = 0; j < 4; ++j) acc[i][j] = fmaf(aa[i], bb[j], acc[i][j]);
        }
    }
    float4 bv = *reinterpret_cast<const float4*>(&bias[bn + tx * 4]);
#pragma unroll
    for (int i = 0; i < 8; ++i) {
        int rr = bm + ty * 8 + i;
        float4 v4 = make_float4(acc[i][0] + bv.x, acc[i][1] + bv.y,
                                acc[i][2] + bv.z, acc[i][3] + bv.w);
        *reinterpret_cast<float4*>(&out[(size_t)rr * CDIM + bn + tx * 4]) = v4;
    }
}

// ---------------------------------------------------------------------------
extern "C" void kernel_launch(void* const* d_in, const int* in_sizes, int n_in,
                              void* d_out, int out_size, void* d_ws, size_t ws_size,
                              hipStream_t stream) {
    const float* x      = (const float*)d_in[0];
    const float* qkv_w  = (const float*)d_in[1];
    const float* proj_w = (const float*)d_in[2];
    const float* proj_b = (const float*)d_in[3];
    const float* temp   = (const float*)d_in[4];
    const int*   topk   = (const int*)d_in[5];
    float* out = (float*)d_out;

    const size_t HSZ = (size_t)NB * NH * NSEQ * HD;  // 3,145,728 elements
    double* Q64  = (double*)d_ws;           // 24 MB
    double* K64  = Q64 + HSZ;               // 24 MB
    float*  Qs32 = (float*)(K64 + HSZ);     // 12 MB
    float*  Kt32 = Qs32 + HSZ;              // 12 MB
    float*  V    = Kt32 + HSZ;              // 12 MB
    float*  AO   = V + HSZ;                 // 12 MB  -> 96 MB total

    qkv_fused<<<dim3(1536), 256, 0, stream>>>(x, qkv_w, Q64, K64, Qs32, Kt32, V);
    attn_kernel<<<dim3(NB * NH * (NSEQ / 8)), 512, 0, stream>>>(Q64, K64, Qs32, Kt32, V, temp, topk, AO);
    proj_gemm<<<dim3(12, 32), 256, 0, stream>>>(AO, proj_w, proj_b, out);
}

// Round 16
// 670.456 us; speedup vs baseline: 1.0529x; 1.0529x over previous
//
#include <hip/hip_runtime.h>
#include <cstdint>

#define NH 12
#define HD 64
#define NSEQ 2048
#define CDIM 768
#define NB 2

typedef __attribute__((ext_vector_type(2))) float f32x2;

// ---------------------------------------------------------------------------
// Kernel 1 (fused): blocks [0,768): Q,K = x @ qkv_w[0:1536]^T, f64 accum,
// 128x64 tile, 8x4/thread, f64 LDS staging (double2 reads), reg-prefetch.
// blocks [768,1536): V = x @ qkv_w[1536:2304]^T, f32, 64x64 tile, 4x4/thread.
// ---------------------------------------------------------------------------
__global__ __launch_bounds__(256, 4) void qkv_fused(const float* __restrict__ x,
                                                    const float* __restrict__ w,
                                                    double* __restrict__ Q64,
                                                    double* __restrict__ K64,
                                                    float* __restrict__ Qs32,
                                                    float* __restrict__ Kt32,
                                                    float* __restrict__ V) {
    __shared__ __align__(16) char smem[24576];
    const int tid = threadIdx.x;

    if (blockIdx.x < 768) {
        // ---------------- Q,K path (f64) ----------------
        double (*As)[128] = reinterpret_cast<double(*)[128]>(smem);          // 16 KB
        double (*Bs)[64]  = reinterpret_cast<double(*)[64]>(smem + 16384);   // 8 KB
        const int bm = (blockIdx.x / 24) * 128;   // M = 4096
        const int bn = (blockIdx.x % 24) * 64;    // N = 1536
        const int alm = tid >> 1, alk = (tid & 1) * 8;
        const int blm = tid & 63, blk = (tid >> 6) * 4;
        const int tx = tid & 15, ty = tid >> 4;

        double acc[8][4] = {};
        float4 a0 = *reinterpret_cast<const float4*>(&x[(bm + alm) * CDIM + alk]);
        float4 a1 = *reinterpret_cast<const float4*>(&x[(bm + alm) * CDIM + alk + 4]);
        float4 b0 = *reinterpret_cast<const float4*>(&w[(bn + blm) * CDIM + blk]);
        for (int k0 = 0; k0 < CDIM; k0 += 16) {
            __syncthreads();
            As[alk + 0][alm] = (double)a0.x; As[alk + 1][alm] = (double)a0.y;
            As[alk + 2][alm] = (double)a0.z; As[alk + 3][alm] = (double)a0.w;
            As[alk + 4][alm] = (double)a1.x; As[alk + 5][alm] = (double)a1.y;
            As[alk + 6][alm] = (double)a1.z; As[alk + 7][alm] = (double)a1.w;
            Bs[blk + 0][blm] = (double)b0.x; Bs[blk + 1][blm] = (double)b0.y;
            Bs[blk + 2][blm] = (double)b0.z; Bs[blk + 3][blm] = (double)b0.w;
            __syncthreads();
            if (k0 + 16 < CDIM) {
                a0 = *reinterpret_cast<const float4*>(&x[(bm + alm) * CDIM + k0 + 16 + alk]);
                a1 = *reinterpret_cast<const float4*>(&x[(bm + alm) * CDIM + k0 + 16 + alk + 4]);
                b0 = *reinterpret_cast<const float4*>(&w[(bn + blm) * CDIM + k0 + 16 + blk]);
            }
#pragma unroll
            for (int k = 0; k < 16; ++k) {
                double2 a01 = *reinterpret_cast<const double2*>(&As[k][ty * 8 + 0]);
                double2 a23 = *reinterpret_cast<const double2*>(&As[k][ty * 8 + 2]);
                double2 a45 = *reinterpret_cast<const double2*>(&As[k][ty * 8 + 4]);
                double2 a67 = *reinterpret_cast<const double2*>(&As[k][ty * 8 + 6]);
                double2 b01 = *reinterpret_cast<const double2*>(&Bs[k][tx * 4 + 0]);
                double2 b23 = *reinterpret_cast<const double2*>(&Bs[k][tx * 4 + 2]);
                double ad[8] = {a01.x, a01.y, a23.x, a23.y, a45.x, a45.y, a67.x, a67.y};
                double bd[4] = {b01.x, b01.y, b23.x, b23.y};
#pragma unroll
                for (int i = 0; i < 8; ++i)
#pragma unroll
                    for (int j = 0; j < 4; ++j) acc[i][j] = fma(ad[i], bd[j], acc[i][j]);
            }
        }
        const bool isQ = bn < CDIM;
        const int hh = (isQ ? bn : bn - CDIM) >> 6;
        const int b  = bm >> 11;
        const int bh = b * NH + hh;
#pragma unroll
        for (int i = 0; i < 8; ++i) {
            const int n = (bm + ty * 8 + i) & (NSEQ - 1);
            const size_t base = ((size_t)bh * NSEQ + n) * HD + tx * 4;
            double2 d01; d01.x = acc[i][0]; d01.y = acc[i][1];
            double2 d23; d23.x = acc[i][2]; d23.y = acc[i][3];
            if (isQ) {
                *reinterpret_cast<double2*>(&Q64[base]) = d01;
                *reinterpret_cast<double2*>(&Q64[base + 2]) = d23;
                *reinterpret_cast<float4*>(&Qs32[base]) =
                    make_float4((float)acc[i][0], (float)acc[i][1], (float)acc[i][2], (float)acc[i][3]);
            } else {
                *reinterpret_cast<double2*>(&K64[base]) = d01;
                *reinterpret_cast<double2*>(&K64[base + 2]) = d23;
#pragma unroll
                for (int j = 0; j < 4; ++j)
                    Kt32[((size_t)bh * HD + tx * 4 + j) * NSEQ + n] = (float)acc[i][j];
            }
        }
    } else {
        // ---------------- V path (f32) ----------------
        float (*As)[64] = reinterpret_cast<float(*)[64]>(smem);              // 4 KB
        float (*Bs)[64] = reinterpret_cast<float(*)[64]>(smem + 4096);       // 4 KB
        const float* __restrict__ wv = w + (size_t)2 * CDIM * CDIM;
        const int vid = blockIdx.x - 768;
        const int bm = (vid / 12) * 64;
        const int bn = (vid % 12) * 64;
        const int lm = tid >> 2;
        const int lk = (tid & 3) << 2;
        const int tx = tid & 15, ty = tid >> 4;

        float acc[4][4] = {};
        float4 av = *reinterpret_cast<const float4*>(&x[(bm + lm) * CDIM + lk]);
        float4 bv = *reinterpret_cast<const float4*>(&wv[(bn + lm) * CDIM + lk]);
        for (int k0 = 0; k0 < CDIM; k0 += 16) {
            __syncthreads();
            As[lk + 0][lm] = av.x; As[lk + 1][lm] = av.y; As[lk + 2][lm] = av.z; As[lk + 3][lm] = av.w;
            Bs[lk + 0][lm] = bv.x; Bs[lk + 1][lm] = bv.y; Bs[lk + 2][lm] = bv.z; Bs[lk + 3][lm] = bv.w;
            __syncthreads();
            if (k0 + 16 < CDIM) {
                av = *reinterpret_cast<const float4*>(&x[(bm + lm) * CDIM + k0 + 16 + lk]);
                bv = *reinterpret_cast<const float4*>(&wv[(bn + lm) * CDIM + k0 + 16 + lk]);
            }
#pragma unroll
            for (int k = 0; k < 16; ++k) {
                float4 a4 = *reinterpret_cast<const float4*>(&As[k][ty * 4]);
                float4 b4 = *reinterpret_cast<const float4*>(&Bs[k][tx * 4]);
                float aa[4] = {a4.x, a4.y, a4.z, a4.w};
                float bb[4] = {b4.x, b4.y, b4.z, b4.w};
#pragma unroll
                for (int i = 0; i < 4; ++i)
#pragma unroll
                    for (int j = 0; j < 4; ++j) acc[i][j] = fmaf(aa[i], bb[j], acc[i][j]);
            }
        }
        const int hh = bn >> 6;
        const int b  = bm >> 11;
#pragma unroll
        for (int i = 0; i < 4; ++i) {
            const int n = (bm + ty * 4 + i) & (NSEQ - 1);
            *reinterpret_cast<float4*>(&V[(((size_t)b * NH + hh) * NSEQ + n) * HD + tx * 4]) =
                make_float4(acc[i][0], acc[i][1], acc[i][2], acc[i][3]);
        }
    }
}

// ---------------------------------------------------------------------------
// Kernel 2: packed-f32 bulk scores -> u16-key candidates (ballot select) ->
// group-coalesced dynamic f64 rescore -> packed 128-wide bitonic (top-64-only
// final merge) -> exact f64 softmax/top-p -> sparse PV.  XCD-swizzled blocks.
// block = 512 threads (8 waves), 8 rows of one (b,h); wave w owns row w.
// (Round-16: reverted round-15's inline-asm v_pk_fma_f32 — it blocked the
// compiler's scheduling and cost +40us; the builtin form is the proven best.)
// ---------------------------------------------------------------------------
__device__ inline unsigned long long d2key(double f) {
    unsigned long long u = (unsigned long long)__double_as_longlong(f);
    return u ^ (unsigned long long)(((long long)u >> 63) | (long long)0x8000000000000000ull);
}
__device__ inline double key2d(unsigned long long k) {
    unsigned long long mask = ((long long)k < 0) ? 0x8000000000000000ull : 0xFFFFFFFFFFFFFFFFull;
    return __longlong_as_double((long long)(k ^ mask));
}
__device__ inline unsigned kp(float a, float b) {
    unsigned ua = __float_as_uint(a);
    ua ^= (unsigned)(((int)ua >> 31) | 0x80000000);
    unsigned ub = __float_as_uint(b);
    ub ^= (unsigned)(((int)ub >> 31) | 0x80000000);
    return (ua >> 16) | (ub & 0xFFFF0000u);
}

__global__ __launch_bounds__(512, 6) void attn_kernel(const double* __restrict__ Q64,
                                                      const double* __restrict__ K64,
                                                      const float* __restrict__ Qs32,
                                                      const float* __restrict__ Kt32,
                                                      const float* __restrict__ V,
                                                      const float* __restrict__ temp,
                                                      const int* __restrict__ topk_p,
                                                      float* __restrict__ AO) {
    __shared__ unsigned short sk[8][NSEQ];   // 32 KB u16 proxy keys (row r's first
                                             // 1 KB later reused as packed-key scratch)
    __shared__ int cand[8][128];

    const int tid  = threadIdx.x;              // 0..511
    // XCD swizzle: nwg=6144 (%8==0). Same-XCD blocks get 768 consecutive work
    // items = 3 whole (b,h) K-panels -> panel stays L2-resident per XCD.
    const int wg   = (blockIdx.x & 7) * 768 + (blockIdx.x >> 3);
    const int bh   = wg >> 8;
    const int g0   = (wg & 255) << 3;
    const int lane = tid & 63;
    const int wv   = tid >> 6;

    const double scale = 0.125 * (double)temp[0];
    const float sc32 = (float)scale;
    int TK = *topk_p;
    if (TK > 64) TK = 64;
    if (TK < 1)  TK = 1;

    // ---- phase 2: raw f32 dots (packed f32x2); thread owns 4 cols x 8 rows.
    const float* __restrict__ kb = Kt32 + (size_t)bh * HD * NSEQ;
    const float* __restrict__ qp = Qs32 + ((size_t)bh * NSEQ + g0) * HD;  // qp[r*64+d]
    const int m0 = tid * 4;
    f32x2 acc2[8][2] = {};
#pragma unroll 4
    for (int d = 0; d < HD; ++d) {
        float4 k4 = *reinterpret_cast<const float4*>(&kb[(size_t)d * NSEQ + m0]);
        f32x2 kA; kA.x = k4.x; kA.y = k4.y;
        f32x2 kB; kB.x = k4.z; kB.y = k4.w;
#pragma unroll
        for (int r8 = 0; r8 < 8; ++r8) {
            float qv = qp[r8 * HD + d];
            f32x2 qq; qq.x = qv; qq.y = qv;
            acc2[r8][0] = __builtin_elementwise_fma(qq, kA, acc2[r8][0]);
            acc2[r8][1] = __builtin_elementwise_fma(qq, kB, acc2[r8][1]);
        }
    }
#pragma unroll
    for (int r8 = 0; r8 < 8; ++r8) {
        uint2 pkv;
        pkv.x = kp(acc2[r8][0].x * sc32, acc2[r8][0].y * sc32);
        pkv.y = kp(acc2[r8][1].x * sc32, acc2[r8][1].y * sc32);
        *reinterpret_cast<uint2*>(&sk[r8][m0]) = pkv;
    }
    __syncthreads();

    // ---- phase 3: wave wv owns row wv
    const int r = wv;
    const int row = g0 + r;

    int k32[32];
#pragma unroll
    for (int i = 0; i < 32; ++i) k32[i] = sk[r][i * 64 + lane];

    // wave max of keys
    int mx = k32[0];
#pragma unroll
    for (int i = 1; i < 32; ++i) mx = max(mx, k32[i]);
#pragma unroll
    for (int off = 32; off > 0; off >>= 1) mx = max(mx, __shfl_xor(mx, off));

    // windowed binary search on u16 keys via ballot+popc:
    // largest lo with count(>=lo) >= TK, stop once that count <= 72.
    int lo0 = mx > 512 ? mx - 512 : 0;
    int c0 = 0;
#pragma unroll
    for (int i = 0; i < 32; ++i) c0 += (int)__popcll(__ballot(k32[i] >= lo0));
    int lo, hi, clo;
    if (c0 >= TK) { lo = lo0; clo = c0; hi = mx; }
    else          { lo = 0;   clo = NSEQ; hi = lo0 - 1; }
    while (lo < hi && clo > 72) {
        int mid = lo + ((hi - lo + 1) >> 1);
        int c = 0;
#pragma unroll
        for (int i = 0; i < 32; ++i) c += (int)__popcll(__ballot(k32[i] >= mid));
        if (c >= TK) { lo = mid; clo = c; } else hi = mid - 1;
    }
    int thr = lo >= 2 ? lo - 2 : 0;   // margin covers f32-dot + trunc error

    // ballot-based compaction of candidate column indices (deterministic order)
    const unsigned long long lmask = (1ull << lane) - 1ull;
    int base = 0;
#pragma unroll
    for (int i = 0; i < 32; ++i) {
        bool pred = k32[i] >= thr;
        unsigned long long bal = __ballot(pred);
        if (pred) {
            int slot = base + (int)__popcll(bal & lmask);
            if (slot < 128) cand[r][slot] = i * 64 + lane;
        }
        base += (int)__popcll(bal);
    }
    int ncand = min(base, 128);
    asm volatile("s_waitcnt lgkmcnt(0)" ::: "memory");

    // ---- group-coalesced dynamic f64 rescore: 8 groups x 8 lanes;
    // iteration j covers slots j*8 + gidx; lane sl reads k[m][sl*8..sl*8+8)
    const int gidx = lane >> 3;
    const int sl   = lane & 7;
    const double* __restrict__ qrow = Q64 + ((size_t)bh * NSEQ + row) * HD;
    double qd[8];
#pragma unroll
    for (int j = 0; j < 8; ++j) qd[j] = qrow[sl * 8 + j];

    // prefetch all candidate indices for this lane's group into registers
    int msArr[16];
#pragma unroll
    for (int j = 0; j < 16; ++j) msArr[j] = cand[r][min(j * 8 + gidx, ncand - 1)];

    unsigned long long* pkr = reinterpret_cast<unsigned long long*>(&sk[r][0]);
    pkr[lane] = 0ull;                 // zero-init packed-key scratch (128 slots)
    pkr[64 + lane] = 0ull;
    const double* __restrict__ kbase = K64 + (size_t)bh * NSEQ * HD;
    const int jmax = (ncand + 7) >> 3;    // wave-uniform
#pragma unroll 2
    for (int j = 0; j < jmax; ++j) {
        const int s = j * 8 + gidx;
        const int ms = msArr[j];
        const double* __restrict__ kp8 = kbase + (size_t)ms * HD + sl * 8;
        double a = 0.0;
#pragma unroll
        for (int d = 0; d < 8; ++d) a = fma(qd[d], kp8[d], a);
        // 8-lane tree reduction (deterministic f64 order)
        a += __shfl_xor(a, 1);
        a += __shfl_xor(a, 2);
        a += __shfl_xor(a, 4);
        a *= scale;
        unsigned long long pkv = (d2key(a) & ~2047ull) | (unsigned long long)(2047 - ms);
        if (sl == (j & 7) && s < ncand) pkr[s] = pkv;
    }
    asm volatile("s_waitcnt lgkmcnt(0)" ::: "memory");
    unsigned long long pk1 = pkr[lane];
    unsigned long long pk2 = pkr[64 + lane];

    // bitonic: sort t0 asc, t1 desc (by t), then top-64-only final merge.
    unsigned long long t0 = ~pk1, t1 = ~pk2;
#pragma unroll
    for (int k = 2; k <= 64; k <<= 1) {
#pragma unroll
        for (int j = k >> 1; j > 0; j >>= 1) {
            {
                unsigned long long ot = __shfl_xor(t0, j);
                bool dir = (lane & k) != 0;
                bool lower = (lane & j) == 0;
                bool takeMin = (lower != dir);
                bool less = t0 < ot;
                t0 = (takeMin == less) ? t0 : ot;
            }
            {
                unsigned long long ot = __shfl_xor(t1, j);
                bool dir = (k == 64) ? true : ((lane & k) != 0);
                bool lower = (lane & j) == 0;
                bool takeMin = (lower != dir);
                bool less = t1 < ot;
                t1 = (takeMin == less) ? t1 : ot;
            }
        }
    }
    // k=128 split: t0 asc + t1 desc is bitonic; after pairwise min, t0 holds
    // the 64 smallest t (= 64 largest keys) as a bitonic sequence. TK <= 64,
    // so t1's merge is dead work — sort only t0.
    t0 = (t1 < t0) ? t1 : t0;
#pragma unroll
    for (int j = 32; j > 0; j >>= 1) {
        unsigned long long ot = __shfl_xor(t0, j);
        bool lower = (lane & j) == 0;
        bool less = t0 < ot;
        t0 = (lower == less) ? t0 : ot;
    }
    // lane l holds l-th largest candidate
    unsigned long long kk = ~t0;
    int mi = 2047 - (int)(kk & 2047ull);
    bool valid = lane < TK;
    double a = valid ? key2d(kk & ~2047ull) : 0.0;
    double amax = __shfl(a, 0);
    double s = valid ? exp(a - amax) : 0.0;

    double ps = s;
#pragma unroll
    for (int off = 1; off < 64; off <<= 1) {
        double tt = __shfl_up(ps, off);
        if (lane >= off) ps += tt;
    }
    double S = __shfl(ps, 63);
    double cumprev = (ps - s) / S;
    bool keep = valid && ((lane == 0) || (cumprev <= 0.9));
    double sk2 = keep ? s : 0.0;
    double S2 = sk2;
#pragma unroll
    for (int off = 32; off > 0; off >>= 1) S2 += __shfl_xor(S2, off);
    float p = (float)(keep ? (s / S2) : 0.0);

    unsigned long long bal = __ballot(keep);
    int nk = __popcll(bal);

    // sparse PV, 4-way accumulators (f32 reorder only; decisions unaffected)
    const float* __restrict__ vb = V + (size_t)bh * NSEQ * HD;
    float o0 = 0.f, o1 = 0.f, o2 = 0.f, o3 = 0.f;
    int i = 0;
    for (; i + 4 <= nk; i += 4) {
        float pa = __shfl(p, i),     pb = __shfl(p, i + 1);
        float pc = __shfl(p, i + 2), pd = __shfl(p, i + 3);
        int ma = __shfl(mi, i),     mb2 = __shfl(mi, i + 1);
        int mc = __shfl(mi, i + 2), md = __shfl(mi, i + 3);
        o0 = fmaf(pa, vb[(size_t)ma * HD + lane], o0);
        o1 = fmaf(pb, vb[(size_t)mb2 * HD + lane], o1);
        o2 = fmaf(pc, vb[(size_t)mc * HD + lane], o2);
        o3 = fmaf(pd, vb[(size_t)md * HD + lane], o3);
    }
    for (; i < nk; ++i) {
        float pi = __shfl(p, i);
        int midx = __shfl(mi, i);
        o0 = fmaf(pi, vb[(size_t)midx * HD + lane], o0);
    }
    float o = (o0 + o1) + (o2 + o3);
    const int b = bh / NH, hh = bh % NH;
    AO[((size_t)b * NSEQ + row) * CDIM + hh * HD + lane] = o;
}

// ---------------------------------------------------------------------------
// Kernel 3: out = AO @ proj_w^T + proj_b   (f32, 128x64 tile, 8x4/thread)
// ---------------------------------------------------------------------------
__global__ __launch_bounds__(256) void proj_gemm(const float* __restrict__ A,
                                                 const float* __restrict__ w,
                                                 const float* __restrict__ bias,
                                                 float* __restrict__ out) {
    __shared__ float As[16][128];
    __shared__ float Bs[16][64];
    const int tid = threadIdx.x;
    const int bm = blockIdx.y * 128;
    const int bn = blockIdx.x * 64;
    const int alm = tid >> 1, alk = (tid & 1) * 8;
    const int blm = tid & 63, blk = (tid >> 6) * 4;
    const int tx = tid & 15, ty = tid >> 4;

    float acc[8][4] = {};
    float4 a0 = *reinterpret_cast<const float4*>(&A[(bm + alm) * CDIM + alk]);
    float4 a1 = *reinterpret_cast<const float4*>(&A[(bm + alm) * CDIM + alk + 4]);
    float4 b0 = *reinterpret_cast<const float4*>(&w[(bn + blm) * CDIM + blk]);
    for (int k0 = 0; k0 < CDIM; k0 += 16) {
        __syncthreads();
        As[alk + 0][alm] = a0.x; As[alk + 1][alm] = a0.y;
        As[alk + 2][alm] = a0.z; As[alk + 3][alm] = a0.w;
        As[alk + 4][alm] = a1.x; As[alk + 5][alm] = a1.y;
        As[alk + 6][alm] = a1.z; As[alk + 7][alm] = a1.w;
        Bs[blk + 0][blm] = b0.x; Bs[blk + 1][blm] = b0.y;
        Bs[blk + 2][blm] = b0.z; Bs[blk + 3][blm] = b0.w;
        __syncthreads();
        if (k0 + 16 < CDIM) {
            a0 = *reinterpret_cast<const float4*>(&A[(bm + alm) * CDIM + k0 + 16 + alk]);
            a1 = *reinterpret_cast<const float4*>(&A[(bm + alm) * CDIM + k0 + 16 + alk + 4]);
            b0 = *reinterpret_cast<const float4*>(&w[(bn + blm) * CDIM + k0 + 16 + blk]);
        }
#pragma unroll
        for (int k = 0; k < 16; ++k) {
            float4 af0 = *reinterpret_cast<const float4*>(&As[k][ty * 8]);
            float4 af1 = *reinterpret_cast<const float4*>(&As[k][ty * 8 + 4]);
            float4 bf  = *reinterpret_cast<const float4*>(&Bs[k][tx * 4]);
            float aa[8] = {af0.x, af0.y, af0.z, af0.w, af1.x, af1.y, af1.z, af1.w};
            float bb[4] = {bf.x, bf.y, bf.z, bf.w};
#pragma unroll
            for (int i = 0; i < 8; ++i)
#pragma unroll
                for (int j = 0; j < 4; ++j) acc[i][j] = fmaf(aa[i], bb[j], acc[i][j]);
        }
    }
    float4 bv = *reinterpret_cast<const float4*>(&bias[bn + tx * 4]);
#pragma unroll
    for (int i = 0; i < 8; ++i) {
        int rr = bm + ty * 8 + i;
        float4 v4 = make_float4(acc[i][0] + bv.x, acc[i][1] + bv.y,
                                acc[i][2] + bv.z, acc[i][3] + bv.w);
        *reinterpret_cast<float4*>(&out[(size_t)rr * CDIM + bn + tx * 4]) = v4;
    }
}

// ---------------------------------------------------------------------------
extern "C" void kernel_launch(void* const* d_in, const int* in_sizes, int n_in,
                              void* d_out, int out_size, void* d_ws, size_t ws_size,
                              hipStream_t stream) {
    const float* x      = (const float*)d_in[0];
    const float* qkv_w  = (const float*)d_in[1];
    const float* proj_w = (const float*)d_in[2];
    const float* proj_b = (const float*)d_in[3];
    const float* temp   = (const float*)d_in[4];
    const int*   topk   = (const int*)d_in[5];
    float* out = (float*)d_out;

    const size_t HSZ = (size_t)NB * NH * NSEQ * HD;  // 3,145,728 elements
    double* Q64  = (double*)d_ws;           // 24 MB
    double* K64  = Q64 + HSZ;               // 24 MB
    float*  Qs32 = (float*)(K64 + HSZ);     // 12 MB
    float*  Kt32 = Qs32 + HSZ;              // 12 MB
    float*  V    = Kt32 + HSZ;              // 12 MB
    float*  AO   = V + HSZ;                 // 12 MB  -> 96 MB total

    qkv_fused<<<dim3(1536), 256, 0, stream>>>(x, qkv_w, Q64, K64, Qs32, Kt32, V);
    attn_kernel<<<dim3(NB * NH * (NSEQ / 8)), 512, 0, stream>>>(Q64, K64, Qs32, Kt32, V, temp, topk, AO);
    proj_gemm<<<dim3(12, 32), 256, 0, stream>>>(AO, proj_w, proj_b, out);
}

// Round 18
// 669.113 us; speedup vs baseline: 1.0550x; 1.0020x over previous
//
#include <hip/hip_runtime.h>
#include <cstdint>

#define NH 12
#define HD 64
#define NSEQ 2048
#define CDIM 768
#define NB 2

typedef __attribute__((ext_vector_type(2))) float f32x2;

// ---------------------------------------------------------------------------
// Kernel 1 (fused): blocks [0,768): Q,K = x @ qkv_w[0:1536]^T, f64 accum,
// 128x64 tile, 8x4/thread, f64 LDS staging (double2 reads), reg-prefetch.
// blocks [768,1536): V = x @ qkv_w[1536:2304]^T, f32, 64x64 tile, 4x4/thread.
// (Round-18: reverted round-17's f64-MFMA experiment — wrong fragment layout,
// and expected payoff (<55us) doesn't justify blind layout debugging.)
// ---------------------------------------------------------------------------
__global__ __launch_bounds__(256, 4) void qkv_fused(const float* __restrict__ x,
                                                    const float* __restrict__ w,
                                                    double* __restrict__ Q64,
                                                    double* __restrict__ K64,
                                                    float* __restrict__ Qs32,
                                                    float* __restrict__ Kt32,
                                                    float* __restrict__ V) {
    __shared__ __align__(16) char smem[24576];
    const int tid = threadIdx.x;

    if (blockIdx.x < 768) {
        // ---------------- Q,K path (f64) ----------------
        double (*As)[128] = reinterpret_cast<double(*)[128]>(smem);          // 16 KB
        double (*Bs)[64]  = reinterpret_cast<double(*)[64]>(smem + 16384);   // 8 KB
        const int bm = (blockIdx.x / 24) * 128;   // M = 4096
        const int bn = (blockIdx.x % 24) * 64;    // N = 1536
        const int alm = tid >> 1, alk = (tid & 1) * 8;
        const int blm = tid & 63, blk = (tid >> 6) * 4;
        const int tx = tid & 15, ty = tid >> 4;

        double acc[8][4] = {};
        float4 a0 = *reinterpret_cast<const float4*>(&x[(bm + alm) * CDIM + alk]);
        float4 a1 = *reinterpret_cast<const float4*>(&x[(bm + alm) * CDIM + alk + 4]);
        float4 b0 = *reinterpret_cast<const float4*>(&w[(bn + blm) * CDIM + blk]);
        for (int k0 = 0; k0 < CDIM; k0 += 16) {
            __syncthreads();
            As[alk + 0][alm] = (double)a0.x; As[alk + 1][alm] = (double)a0.y;
            As[alk + 2][alm] = (double)a0.z; As[alk + 3][alm] = (double)a0.w;
            As[alk + 4][alm] = (double)a1.x; As[alk + 5][alm] = (double)a1.y;
            As[alk + 6][alm] = (double)a1.z; As[alk + 7][alm] = (double)a1.w;
            Bs[blk + 0][blm] = (double)b0.x; Bs[blk + 1][blm] = (double)b0.y;
            Bs[blk + 2][blm] = (double)b0.z; Bs[blk + 3][blm] = (double)b0.w;
            __syncthreads();
            if (k0 + 16 < CDIM) {
                a0 = *reinterpret_cast<const float4*>(&x[(bm + alm) * CDIM + k0 + 16 + alk]);
                a1 = *reinterpret_cast<const float4*>(&x[(bm + alm) * CDIM + k0 + 16 + alk + 4]);
                b0 = *reinterpret_cast<const float4*>(&w[(bn + blm) * CDIM + k0 + 16 + blk]);
            }
#pragma unroll
            for (int k = 0; k < 16; ++k) {
                double2 a01 = *reinterpret_cast<const double2*>(&As[k][ty * 8 + 0]);
                double2 a23 = *reinterpret_cast<const double2*>(&As[k][ty * 8 + 2]);
                double2 a45 = *reinterpret_cast<const double2*>(&As[k][ty * 8 + 4]);
                double2 a67 = *reinterpret_cast<const double2*>(&As[k][ty * 8 + 6]);
                double2 b01 = *reinterpret_cast<const double2*>(&Bs[k][tx * 4 + 0]);
                double2 b23 = *reinterpret_cast<const double2*>(&Bs[k][tx * 4 + 2]);
                double ad[8] = {a01.x, a01.y, a23.x, a23.y, a45.x, a45.y, a67.x, a67.y};
                double bd[4] = {b01.x, b01.y, b23.x, b23.y};
#pragma unroll
                for (int i = 0; i < 8; ++i)
#pragma unroll
                    for (int j = 0; j < 4; ++j) acc[i][j] = fma(ad[i], bd[j], acc[i][j]);
            }
        }
        const bool isQ = bn < CDIM;
        const int hh = (isQ ? bn : bn - CDIM) >> 6;
        const int b  = bm >> 11;
        const int bh = b * NH + hh;
#pragma unroll
        for (int i = 0; i < 8; ++i) {
            const int n = (bm + ty * 8 + i) & (NSEQ - 1);
            const size_t base = ((size_t)bh * NSEQ + n) * HD + tx * 4;
            double2 d01; d01.x = acc[i][0]; d01.y = acc[i][1];
            double2 d23; d23.x = acc[i][2]; d23.y = acc[i][3];
            if (isQ) {
                *reinterpret_cast<double2*>(&Q64[base]) = d01;
                *reinterpret_cast<double2*>(&Q64[base + 2]) = d23;
                *reinterpret_cast<float4*>(&Qs32[base]) =
                    make_float4((float)acc[i][0], (float)acc[i][1], (float)acc[i][2], (float)acc[i][3]);
            } else {
                *reinterpret_cast<double2*>(&K64[base]) = d01;
                *reinterpret_cast<double2*>(&K64[base + 2]) = d23;
#pragma unroll
                for (int j = 0; j < 4; ++j)
                    Kt32[((size_t)bh * HD + tx * 4 + j) * NSEQ + n] = (float)acc[i][j];
            }
        }
    } else {
        // ---------------- V path (f32) ----------------
        float (*As)[64] = reinterpret_cast<float(*)[64]>(smem);              // 4 KB
        float (*Bs)[64] = reinterpret_cast<float(*)[64]>(smem + 4096);       // 4 KB
        const float* __restrict__ wv = w + (size_t)2 * CDIM * CDIM;
        const int vid = blockIdx.x - 768;
        const int bm = (vid / 12) * 64;
        const int bn = (vid % 12) * 64;
        const int lm = tid >> 2;
        const int lk = (tid & 3) << 2;
        const int tx = tid & 15, ty = tid >> 4;

        float acc[4][4] = {};
        float4 av = *reinterpret_cast<const float4*>(&x[(bm + lm) * CDIM + lk]);
        float4 bv = *reinterpret_cast<const float4*>(&wv[(bn + lm) * CDIM + lk]);
        for (int k0 = 0; k0 < CDIM; k0 += 16) {
            __syncthreads();
            As[lk + 0][lm] = av.x; As[lk + 1][lm] = av.y; As[lk + 2][lm] = av.z; As[lk + 3][lm] = av.w;
            Bs[lk + 0][lm] = bv.x; Bs[lk + 1][lm] = bv.y; Bs[lk + 2][lm] = bv.z; Bs[lk + 3][lm] = bv.w;
            __syncthreads();
            if (k0 + 16 < CDIM) {
                av = *reinterpret_cast<const float4*>(&x[(bm + lm) * CDIM + k0 + 16 + lk]);
                bv = *reinterpret_cast<const float4*>(&wv[(bn + lm) * CDIM + k0 + 16 + lk]);
            }
#pragma unroll
            for (int k = 0; k < 16; ++k) {
                float4 a4 = *reinterpret_cast<const float4*>(&As[k][ty * 4]);
                float4 b4 = *reinterpret_cast<const float4*>(&Bs[k][tx * 4]);
                float aa[4] = {a4.x, a4.y, a4.z, a4.w};
                float bb[4] = {b4.x, b4.y, b4.z, b4.w};
#pragma unroll
                for (int i = 0; i < 4; ++i)
#pragma unroll
                    for (int j = 0; j < 4; ++j) acc[i][j] = fmaf(aa[i], bb[j], acc[i][j]);
            }
        }
        const int hh = bn >> 6;
        const int b  = bm >> 11;
#pragma unroll
        for (int i = 0; i < 4; ++i) {
            const int n = (bm + ty * 4 + i) & (NSEQ - 1);
            *reinterpret_cast<float4*>(&V[(((size_t)b * NH + hh) * NSEQ + n) * HD + tx * 4]) =
                make_float4(acc[i][0], acc[i][1], acc[i][2], acc[i][3]);
        }
    }
}

// ---------------------------------------------------------------------------
// Kernel 2: packed-f32 bulk scores -> u16-key candidates (ballot select) ->
// group-coalesced dynamic f64 rescore -> packed 128-wide bitonic (top-64-only
// final merge) -> exact f64 softmax/top-p -> sparse PV.  XCD-swizzled blocks.
// block = 512 threads (8 waves), 8 rows of one (b,h); wave w owns row w.
// ---------------------------------------------------------------------------
__device__ inline unsigned long long d2key(double f) {
    unsigned long long u = (unsigned long long)__double_as_longlong(f);
    return u ^ (unsigned long long)(((long long)u >> 63) | (long long)0x8000000000000000ull);
}
__device__ inline double key2d(unsigned long long k) {
    unsigned long long mask = ((long long)k < 0) ? 0x8000000000000000ull : 0xFFFFFFFFFFFFFFFFull;
    return __longlong_as_double((long long)(k ^ mask));
}
__device__ inline unsigned kp(float a, float b) {
    unsigned ua = __float_as_uint(a);
    ua ^= (unsigned)(((int)ua >> 31) | 0x80000000);
    unsigned ub = __float_as_uint(b);
    ub ^= (unsigned)(((int)ub >> 31) | 0x80000000);
    return (ua >> 16) | (ub & 0xFFFF0000u);
}

__global__ __launch_bounds__(512, 6) void attn_kernel(const double* __restrict__ Q64,
                                                      const double* __restrict__ K64,
                                                      const float* __restrict__ Qs32,
                                                      const float* __restrict__ Kt32,
                                                      const float* __restrict__ V,
                                                      const float* __restrict__ temp,
                                                      const int* __restrict__ topk_p,
                                                      float* __restrict__ AO) {
    __shared__ unsigned short sk[8][NSEQ];   // 32 KB u16 proxy keys (row r's first
                                             // 1 KB later reused as packed-key scratch)
    __shared__ int cand[8][128];

    const int tid  = threadIdx.x;              // 0..511
    // XCD swizzle: nwg=6144 (%8==0). Same-XCD blocks get 768 consecutive work
    // items = 3 whole (b,h) K-panels -> panel stays L2-resident per XCD.
    const int wg   = (blockIdx.x & 7) * 768 + (blockIdx.x >> 3);
    const int bh   = wg >> 8;
    const int g0   = (wg & 255) << 3;
    const int lane = tid & 63;
    const int wv   = tid >> 6;

    const double scale = 0.125 * (double)temp[0];
    const float sc32 = (float)scale;
    int TK = *topk_p;
    if (TK > 64) TK = 64;
    if (TK < 1)  TK = 1;

    // ---- phase 2: raw f32 dots (packed f32x2); thread owns 4 cols x 8 rows.
    const float* __restrict__ kb = Kt32 + (size_t)bh * HD * NSEQ;
    const float* __restrict__ qp = Qs32 + ((size_t)bh * NSEQ + g0) * HD;  // qp[r*64+d]
    const int m0 = tid * 4;
    f32x2 acc2[8][2] = {};
#pragma unroll 4
    for (int d = 0; d < HD; ++d) {
        float4 k4 = *reinterpret_cast<const float4*>(&kb[(size_t)d * NSEQ + m0]);
        f32x2 kA; kA.x = k4.x; kA.y = k4.y;
        f32x2 kB; kB.x = k4.z; kB.y = k4.w;
#pragma unroll
        for (int r8 = 0; r8 < 8; ++r8) {
            float qv = qp[r8 * HD + d];
            f32x2 qq; qq.x = qv; qq.y = qv;
            acc2[r8][0] = __builtin_elementwise_fma(qq, kA, acc2[r8][0]);
            acc2[r8][1] = __builtin_elementwise_fma(qq, kB, acc2[r8][1]);
        }
    }
#pragma unroll
    for (int r8 = 0; r8 < 8; ++r8) {
        uint2 pkv;
        pkv.x = kp(acc2[r8][0].x * sc32, acc2[r8][0].y * sc32);
        pkv.y = kp(acc2[r8][1].x * sc32, acc2[r8][1].y * sc32);
        *reinterpret_cast<uint2*>(&sk[r8][m0]) = pkv;
    }
    __syncthreads();

    // ---- phase 3: wave wv owns row wv
    const int r = wv;
    const int row = g0 + r;

    int k32[32];
#pragma unroll
    for (int i = 0; i < 32; ++i) k32[i] = sk[r][i * 64 + lane];

    // wave max of keys
    int mx = k32[0];
#pragma unroll
    for (int i = 1; i < 32; ++i) mx = max(mx, k32[i]);
#pragma unroll
    for (int off = 32; off > 0; off >>= 1) mx = max(mx, __shfl_xor(mx, off));

    // windowed binary search on u16 keys via ballot+popc:
    // largest lo with count(>=lo) >= TK, stop once that count <= 72.
    int lo0 = mx > 512 ? mx - 512 : 0;
    int c0 = 0;
#pragma unroll
    for (int i = 0; i < 32; ++i) c0 += (int)__popcll(__ballot(k32[i] >= lo0));
    int lo, hi, clo;
    if (c0 >= TK) { lo = lo0; clo = c0; hi = mx; }
    else          { lo = 0;   clo = NSEQ; hi = lo0 - 1; }
    while (lo < hi && clo > 72) {
        int mid = lo + ((hi - lo + 1) >> 1);
        int c = 0;
#pragma unroll
        for (int i = 0; i < 32; ++i) c += (int)__popcll(__ballot(k32[i] >= mid));
        if (c >= TK) { lo = mid; clo = c; } else hi = mid - 1;
    }
    int thr = lo >= 2 ? lo - 2 : 0;   // margin covers f32-dot + trunc error

    // ballot-based compaction of candidate column indices (deterministic order)
    const unsigned long long lmask = (1ull << lane) - 1ull;
    int base = 0;
#pragma unroll
    for (int i = 0; i < 32; ++i) {
        bool pred = k32[i] >= thr;
        unsigned long long bal = __ballot(pred);
        if (pred) {
            int slot = base + (int)__popcll(bal & lmask);
            if (slot < 128) cand[r][slot] = i * 64 + lane;
        }
        base += (int)__popcll(bal);
    }
    int ncand = min(base, 128);
    asm volatile("s_waitcnt lgkmcnt(0)" ::: "memory");

    // ---- group-coalesced dynamic f64 rescore: 8 groups x 8 lanes;
    // iteration j covers slots j*8 + gidx; lane sl reads k[m][sl*8..sl*8+8)
    const int gidx = lane >> 3;
    const int sl   = lane & 7;
    const double* __restrict__ qrow = Q64 + ((size_t)bh * NSEQ + row) * HD;
    double qd[8];
#pragma unroll
    for (int j = 0; j < 8; ++j) qd[j] = qrow[sl * 8 + j];

    // prefetch all candidate indices for this lane's group into registers
    int msArr[16];
#pragma unroll
    for (int j = 0; j < 16; ++j) msArr[j] = cand[r][min(j * 8 + gidx, ncand - 1)];

    unsigned long long* pkr = reinterpret_cast<unsigned long long*>(&sk[r][0]);
    pkr[lane] = 0ull;                 // zero-init packed-key scratch (128 slots)
    pkr[64 + lane] = 0ull;
    const double* __restrict__ kbase = K64 + (size_t)bh * NSEQ * HD;
    const int jmax = (ncand + 7) >> 3;    // wave-uniform
#pragma unroll 2
    for (int j = 0; j < jmax; ++j) {
        const int s = j * 8 + gidx;
        const int ms = msArr[j];
        const double* __restrict__ kp8 = kbase + (size_t)ms * HD + sl * 8;
        double a = 0.0;
#pragma unroll
        for (int d = 0; d < 8; ++d) a = fma(qd[d], kp8[d], a);
        // 8-lane tree reduction (deterministic f64 order)
        a += __shfl_xor(a, 1);
        a += __shfl_xor(a, 2);
        a += __shfl_xor(a, 4);
        a *= scale;
        unsigned long long pkv = (d2key(a) & ~2047ull) | (unsigned long long)(2047 - ms);
        if (sl == (j & 7) && s < ncand) pkr[s] = pkv;
    }
    asm volatile("s_waitcnt lgkmcnt(0)" ::: "memory");
    unsigned long long pk1 = pkr[lane];
    unsigned long long pk2 = pkr[64 + lane];

    // bitonic: sort t0 asc, t1 desc (by t), then top-64-only final merge.
    unsigned long long t0 = ~pk1, t1 = ~pk2;
#pragma unroll
    for (int k = 2; k <= 64; k <<= 1) {
#pragma unroll
        for (int j = k >> 1; j > 0; j >>= 1) {
            {
                unsigned long long ot = __shfl_xor(t0, j);
                bool dir = (lane & k) != 0;
                bool lower = (lane & j) == 0;
                bool takeMin = (lower != dir);
                bool less = t0 < ot;
                t0 = (takeMin == less) ? t0 : ot;
            }
            {
                unsigned long long ot = __shfl_xor(t1, j);
                bool dir = (k == 64) ? true : ((lane & k) != 0);
                bool lower = (lane & j) == 0;
                bool takeMin = (lower != dir);
                bool less = t1 < ot;
                t1 = (takeMin == less) ? t1 : ot;
            }
        }
    }
    // k=128 split: t0 asc + t1 desc is bitonic; after pairwise min, t0 holds
    // the 64 smallest t (= 64 largest keys) as a bitonic sequence. TK <= 64,
    // so t1's merge is dead work — sort only t0.
    t0 = (t1 < t0) ? t1 : t0;
#pragma unroll
    for (int j = 32; j > 0; j >>= 1) {
        unsigned long long ot = __shfl_xor(t0, j);
        bool lower = (lane & j) == 0;
        bool less = t0 < ot;
        t0 = (lower == less) ? t0 : ot;
    }
    // lane l holds l-th largest candidate
    unsigned long long kk = ~t0;
    int mi = 2047 - (int)(kk & 2047ull);
    bool valid = lane < TK;
    double a = valid ? key2d(kk & ~2047ull) : 0.0;
    double amax = __shfl(a, 0);
    double s = valid ? exp(a - amax) : 0.0;

    double ps = s;
#pragma unroll
    for (int off = 1; off < 64; off <<= 1) {
        double tt = __shfl_up(ps, off);
        if (lane >= off) ps += tt;
    }
    double S = __shfl(ps, 63);
    double cumprev = (ps - s) / S;
    bool keep = valid && ((lane == 0) || (cumprev <= 0.9));
    double sk2 = keep ? s : 0.0;
    double S2 = sk2;
#pragma unroll
    for (int off = 32; off > 0; off >>= 1) S2 += __shfl_xor(S2, off);
    float p = (float)(keep ? (s / S2) : 0.0);

    unsigned long long bal = __ballot(keep);
    int nk = __popcll(bal);

    // sparse PV, 4-way accumulators (f32 reorder only; decisions unaffected)
    const float* __restrict__ vb = V + (size_t)bh * NSEQ * HD;
    float o0 = 0.f, o1 = 0.f, o2 = 0.f, o3 = 0.f;
    int i = 0;
    for (; i + 4 <= nk; i += 4) {
        float pa = __shfl(p, i),     pb = __shfl(p, i + 1);
        float pc = __shfl(p, i + 2), pd = __shfl(p, i + 3);
        int ma = __shfl(mi, i),     mb2 = __shfl(mi, i + 1);
        int mc = __shfl(mi, i + 2), md = __shfl(mi, i + 3);
        o0 = fmaf(pa, vb[(size_t)ma * HD + lane], o0);
        o1 = fmaf(pb, vb[(size_t)mb2 * HD + lane], o1);
        o2 = fmaf(pc, vb[(size_t)mc * HD + lane], o2);
        o3 = fmaf(pd, vb[(size_t)md * HD + lane], o3);
    }
    for (; i < nk; ++i) {
        float pi = __shfl(p, i);
        int midx = __shfl(mi, i);
        o0 = fmaf(pi, vb[(size_t)midx * HD + lane], o0);
    }
    float o = (o0 + o1) + (o2 + o3);
    const int b = bh / NH, hh = bh % NH;
    AO[((size_t)b * NSEQ + row) * CDIM + hh * HD + lane] = o;
}

// ---------------------------------------------------------------------------
// Kernel 3: out = AO @ proj_w^T + proj_b   (f32, 128x64 tile, 8x4/thread)
// ---------------------------------------------------------------------------
__global__ __launch_bounds__(256) void proj_gemm(const float* __restrict__ A,
                                                 const float* __restrict__ w,
                                                 const float* __restrict__ bias,
                                                 float* __restrict__ out) {
    __shared__ float As[16][128];
    __shared__ float Bs[16][64];
    const int tid = threadIdx.x;
    const int bm = blockIdx.y * 128;
    const int bn = blockIdx.x * 64;
    const int alm = tid >> 1, alk = (tid & 1) * 8;
    const int blm = tid & 63, blk = (tid >> 6) * 4;
    const int tx = tid & 15, ty = tid >> 4;

    float acc[8][4] = {};
    float4 a0 = *reinterpret_cast<const float4*>(&A[(bm + alm) * CDIM + alk]);
    float4 a1 = *reinterpret_cast<const float4*>(&A[(bm + alm) * CDIM + alk + 4]);
    float4 b0 = *reinterpret_cast<const float4*>(&w[(bn + blm) * CDIM + blk]);
    for (int k0 = 0; k0 < CDIM; k0 += 16) {
        __syncthreads();
        As[alk + 0][alm] = a0.x; As[alk + 1][alm] = a0.y;
        As[alk + 2][alm] = a0.z; As[alk + 3][alm] = a0.w;
        As[alk + 4][alm] = a1.x; As[alk + 5][alm] = a1.y;
        As[alk + 6][alm] = a1.z; As[alk + 7][alm] = a1.w;
        Bs[blk + 0][blm] = b0.x; Bs[blk + 1][blm] = b0.y;
        Bs[blk + 2][blm] = b0.z; Bs[blk + 3][blm] = b0.w;
        __syncthreads();
        if (k0 + 16 < CDIM) {
            a0 = *reinterpret_cast<const float4*>(&A[(bm + alm) * CDIM + k0 + 16 + alk]);
            a1 = *reinterpret_cast<const float4*>(&A[(bm + alm) * CDIM + k0 + 16 + alk + 4]);
            b0 = *reinterpret_cast<const float4*>(&w[(bn + blm) * CDIM + k0 + 16 + blk]);
        }
#pragma unroll
        for (int k = 0; k < 16; ++k) {
            float4 af0 = *reinterpret_cast<const float4*>(&As[k][ty * 8]);
            float4 af1 = *reinterpret_cast<const float4*>(&As[k][ty * 8 + 4]);
            float4 bf  = *reinterpret_cast<const float4*>(&Bs[k][tx * 4]);
            float aa[8] = {af0.x, af0.y, af0.z, af0.w, af1.x, af1.y, af1.z, af1.w};
            float bb[4] = {bf.x, bf.y, bf.z, bf.w};
#pragma unroll
            for (int i = 0; i < 8; ++i)
#pragma unroll
                for (int j = 0; j < 4; ++j) acc[i][j] = fmaf(aa[i], bb[j], acc[i][j]);
        }
    }
    float4 bv = *reinterpret_cast<const float4*>(&bias[bn + tx * 4]);
#pragma unroll
    for (int i = 0; i < 8; ++i) {
        int rr = bm + ty * 8 + i;
        float4 v4 = make_float4(acc[i][0] + bv.x, acc[i][1] + bv.y,
                                acc[i][2] + bv.z, acc[i][3] + bv.w);
        *reinterpret_cast<float4*>(&out[(size_t)rr * CDIM + bn + tx * 4]) = v4;
    }
}

// ---------------------------------------------------------------------------
extern "C" void kernel_launch(void* const* d_in, const int* in_sizes, int n_in,
                              void* d_out, int out_size, void* d_ws, size_t ws_size,
                              hipStream_t stream) {
    const float* x      = (const float*)d_in[0];
    const float* qkv_w  = (const float*)d_in[1];
    const float* proj_w = (const float*)d_in[2];
    const float* proj_b = (const float*)d_in[3];
    const float* temp   = (const float*)d_in[4];
    const int*   topk   = (const int*)d_in[5];
    float* out = (float*)d_out;

    const size_t HSZ = (size_t)NB * NH * NSEQ * HD;  // 3,145,728 elements
    double* Q64  = (double*)d_ws;           // 24 MB
    double* K64  = Q64 + HSZ;               // 24 MB
    float*  Qs32 = (float*)(K64 + HSZ);     // 12 MB
    float*  Kt32 = Qs32 + HSZ;              // 12 MB
    float*  V    = Kt32 + HSZ;              // 12 MB
    float*  AO   = V + HSZ;                 // 12 MB  -> 96 MB total

    qkv_fused<<<dim3(1536), 256, 0, stream>>>(x, qkv_w, Q64, K64, Qs32, Kt32, V);
    attn_kernel<<<dim3(NB * NH * (NSEQ / 8)), 512, 0, stream>>>(Q64, K64, Qs32, Kt32, V, temp, topk, AO);
    proj_gemm<<<dim3(12, 32), 256, 0, stream>>>(AO, proj_w, proj_b, out);
}